// Round 3
// baseline (692.416 us; speedup 1.0000x reference)
//
#include <hip/hip_runtime.h>
#include <hip/hip_bf16.h>

// Problem constants (B=4, S=4096, IN_F=OUT_F=4096, G=32, GS=GO=128)
#define G_TOT   32
#define GS_     128
#define GO_     128
#define IN_F    4096
#define NROWS   16384                              // B*S
#define ROWS_PER_BLOCK 64
#define NBLOCKS ((NROWS / ROWS_PER_BLOCK) * G_TOT) // 256*32 = 8192
#define THREADS 256

typedef __attribute__((ext_vector_type(4))) float f32x4;
typedef __attribute__((ext_vector_type(8))) short bf16x8;

__device__ __forceinline__ short f2bf(float f) {
  union { __hip_bfloat16 h; short s; } u;
  u.h = __float2bfloat16(f);
  return u.s;
}

// ---- prep 1: robust perm -> int32 BYTE offsets (handles int64 or int32 storage) ----
// If the 4096-permutation is stored little-endian int64 (values < 4096), every odd
// dword of the first 1 KB is zero. Stored int32, those dwords are perm values (at
// most one zero among them) -> discriminates with certainty. The sniff touches only
// the first 1 KB, always in-bounds for either storage width.
__global__ void prep_perm(const void* __restrict__ perm_raw, int* __restrict__ pofs) {
  __shared__ int is64;
  if (threadIdx.x == 0) {
    const int* p32 = (const int*)perm_raw;
    int allzero = 1;
    for (int i = 1; i < 256; i += 2) allzero &= (p32[i] == 0);
    is64 = allzero;
  }
  __syncthreads();
  int i64 = is64;
  for (int j = threadIdx.x; j < IN_F; j += blockDim.x) {
    int v = i64 ? (int)(((const long long*)perm_raw)[j]) : ((const int*)perm_raw)[j];
    pofs[j] = v * 4;  // byte offset into an f32 row
  }
}

// ---- prep 2: W f32 -> bf16, same [G][GO][GS] layout ----
__global__ void prep_w(const float* __restrict__ W, __hip_bfloat16* __restrict__ Wb, int n) {
  int i = blockIdx.x * blockDim.x + threadIdx.x;
  if (i < n) Wb[i] = __float2bfloat16(W[i]);
}

// ---- main: block-diagonal GEMM with gathered-permuted A, bf16 MFMA ----
// grid: 8192 blocks = 256 row-tiles x 32 groups (group fastest), XCD-chunk-swizzled
// so all 32 group-blocks of a row-tile share one XCD's L2 (x rows reused 32x).
// block: 256 thr (4 waves); wave w -> rows [rt*64 + w*16, +16), all 128 outputs of group g.
template<bool USE_WS>
__global__ __launch_bounds__(THREADS, 4) void blockdiag_gemm(
    const float* __restrict__ x,
    const int*   __restrict__ pidx,    // USE_WS: byte offsets; else raw int32 perm
    const void*  __restrict__ wptr,    // USE_WS: bf16 W; else f32 W
    const float* __restrict__ bias,
    float* __restrict__ out)
{
  int bid  = blockIdx.x;
  // chunked XCD swizzle: XCD x gets contiguous wgids [x*1024, (x+1)*1024)
  int wgid = (bid & 7) * (NBLOCKS / 8) + (bid >> 3);
  int rt   = wgid >> 5;      // row tile 0..255
  int g    = wgid & 31;      // group   0..31
  int wave = threadIdx.x >> 6;
  int lane = threadIdx.x & 63;
  int l15  = lane & 15;
  int q    = lane >> 4;      // 0..3

  int rowbase = rt * ROWS_PER_BLOCK + wave * 16;
  const char* xrow = (const char*)(x + (size_t)(rowbase + l15) * IN_F);

  // A fragments: 4 K-steps of 32; lane holds k = ks*32 + q*8 + j.
  // The (q,j)->k map is identical on the A and B sides, so the HW's internal
  // k ordering cancels; only the A-row (lane&15) / B-col (lane&15) and the
  // C/D mapping below must be layout-exact.
  bf16x8 a[4];
  #pragma unroll
  for (int ks = 0; ks < 4; ++ks) {
    int kbase = g * GS_ + ks * 32 + q * 8;
    int4 p0 = *(const int4*)(pidx + kbase);
    int4 p1 = *(const int4*)(pidx + kbase + 4);
    int po[8] = { p0.x, p0.y, p0.z, p0.w, p1.x, p1.y, p1.z, p1.w };
    #pragma unroll
    for (int j = 0; j < 8; ++j) {
      int byteoff = USE_WS ? po[j] : (po[j] * 4);
      float xv = *(const float*)(xrow + byteoff);
      a[ks][j] = f2bf(xv);
    }
  }

  const __hip_bfloat16* Wb = (const __hip_bfloat16*)wptr;
  const float*          Wf = (const float*)wptr;

  #pragma unroll
  for (int n = 0; n < 8; ++n) {
    int ocol = g * GO_ + n * 16 + l15;          // global output column
    float bv = bias[ocol];                      // b is [G][GO] flat == ocol
    f32x4 acc = { bv, bv, bv, bv };             // bias folded into C-init (same col, 4 rows)
    #pragma unroll
    for (int ks = 0; ks < 4; ++ks) {
      bf16x8 bfrag;
      if (USE_WS) {
        bfrag = *(const bf16x8*)(Wb + ((size_t)ocol * GS_ + ks * 32 + q * 8));
      } else {
        const float* wsrc = Wf + ((size_t)ocol * GS_ + ks * 32 + q * 8);
        f32x4 w0 = *(const f32x4*)(wsrc);
        f32x4 w1 = *(const f32x4*)(wsrc + 4);
        #pragma unroll
        for (int j = 0; j < 4; ++j) { bfrag[j] = f2bf(w0[j]); bfrag[4 + j] = f2bf(w1[j]); }
      }
      acc = __builtin_amdgcn_mfma_f32_16x16x32_bf16(a[ks], bfrag, acc, 0, 0, 0);
    }
    // C/D layout (m89-verified): col = lane&15, row = (lane>>4)*4 + reg
    float* obase = out + (size_t)(rowbase + q * 4) * IN_F + ocol;
    #pragma unroll
    for (int r = 0; r < 4; ++r)
      obase[(size_t)r * IN_F] = acc[r];
  }
}

extern "C" void kernel_launch(void* const* d_in, const int* in_sizes, int n_in,
                              void* d_out, int out_size, void* d_ws, size_t ws_size,
                              hipStream_t stream) {
  const float* x    = (const float*)d_in[0];
  const void*  perm = d_in[1];
  const float* W    = (const float*)d_in[2];
  const float* bias = (const float*)d_in[3];
  float* out        = (float*)d_out;

  const size_t pofs_bytes = IN_F * sizeof(int);                    // 16 KB
  const size_t wb_bytes   = (size_t)G_TOT * GO_ * GS_ * 2;         // 1 MB
  const size_t need       = pofs_bytes + wb_bytes;

  if (d_ws && ws_size >= need) {
    int* pofs = (int*)d_ws;
    __hip_bfloat16* Wb = (__hip_bfloat16*)((char*)d_ws + pofs_bytes);
    hipLaunchKernelGGL(prep_perm, dim3(1), dim3(256), 0, stream, perm, pofs);
    hipLaunchKernelGGL(prep_w, dim3((G_TOT * GO_ * GS_ + 255) / 256), dim3(256), 0, stream,
                       W, Wb, G_TOT * GO_ * GS_);
    hipLaunchKernelGGL((blockdiag_gemm<true>), dim3(NBLOCKS), dim3(THREADS), 0, stream,
                       x, pofs, (const void*)Wb, bias, out);
  } else {
    // fallback: no workspace — read perm as int32 (harness doc) and W as f32 inline
    hipLaunchKernelGGL((blockdiag_gemm<false>), dim3(NBLOCKS), dim3(THREADS), 0, stream,
                       x, (const int*)perm, (const void*)W, bias, out);
  }
}